// Round 2
// baseline (429.263 us; speedup 1.0000x reference)
//
#include <hip/hip_runtime.h>

// HierarchicalRouter: 32768 tokens x D=2048 fp32.
// Outputs (concat in d_out): final_weights [32768,2], dispatch_mask [32768,64], router_loss [1].
//
// Round-2 lesson: group logits are near-ties (Wg ~ 0.001 scale); ANY change to the
// accumulation order risks flipping an argmax vs the np reference (absmax jumps from
// 2.4e-4 to ~3.4e-2 = one final weight). This version keeps round-0's BIT-EXACT
// accumulation: same lane-of-64 float4 slice layout, same 8-chunk sequential order,
// same dot4 expression, same 64-lane XOR butterfly (fp add is commutative, so the
// butterfly tree is bitwise order-independent per step).
// Speed changes are all value-neutral:
//  - no LDS weight staging, no per-chunk __syncthreads(): weights read directly from
//    global (20 KB/chunk, L1/L2-resident; identical values to the staged copy).
//  - x software-pipelined in registers (ping-pong, chunk order preserved 0..7) with
//    nontemporal loads: the 268 MB x-stream stays in flight and doesn't evict weights.

#define NTOK    32768
#define DIM     2048
#define NG      16      // router groups (rows of Wg)
#define GS      4       // experts per group (rows of We)
#define NE      64      // total experts
#define NR      20      // NG + GS stacked weight rows
#define DC      256     // D-chunk: 64 lanes x float4
#define NCHUNK  (DIM / DC)
#define TPB     256
#define TPW     4       // tokens per wave (same as round-0)
#define TPBK    16      // tokens per block (4 waves * 4)
#define NSHADOW 32      // shadow copies of expert_load to spread atomic contention

typedef float f4 __attribute__((ext_vector_type(4)));

__device__ __forceinline__ f4 ldnt(const float* p) {
    return __builtin_nontemporal_load((const f4*)p);
}

__global__ __launch_bounds__(TPB, 2) void router_main(
    const float* __restrict__ x,
    const float* __restrict__ Wg,
    const float* __restrict__ We,
    float* __restrict__ fw_out,
    float* __restrict__ dm_out,
    float* __restrict__ ws)
{
    __shared__ float lds_load[NE];    // per-block expert load
    __shared__ float lds_z;           // per-block z-loss partial

    const int tid  = threadIdx.x;
    const int lane = tid & 63;
    const int wave = tid >> 6;
    const long t_base = (long)blockIdx.x * TPBK + wave * TPW;

    if (tid < NE) lds_load[tid] = 0.0f;
    if (tid == 0) lds_z = 0.0f;
    __syncthreads();   // only barrier before the final aggregation

    float acc[TPW][NR];
    #pragma unroll
    for (int t = 0; t < TPW; ++t)
        #pragma unroll
        for (int r = 0; r < NR; ++r) acc[t][r] = 0.0f;

    // ---- barrier-free streaming loop; chunk order 0..7 exactly as round-0 ----
    f4 xa[TPW], xb[TPW];
    #pragma unroll
    for (int t = 0; t < TPW; ++t)
        xa[t] = ldnt(x + (size_t)(t_base + t) * DIM + lane * 4);

    #pragma unroll 1
    for (int c = 0; c < NCHUNK; c += 2) {
        // prefetch chunk c+1
        #pragma unroll
        for (int t = 0; t < TPW; ++t)
            xb[t] = ldnt(x + (size_t)(t_base + t) * DIM + (c + 1) * DC + lane * 4);

        // compute chunk c (weights straight from global; same values as staged copy)
        #pragma unroll
        for (int r = 0; r < NR; ++r) {
            const float* wp = (r < NG) ? (Wg + (size_t)r * DIM)
                                       : (We + (size_t)(r - NG) * DIM);
            f4 w = *(const f4*)(wp + c * DC + lane * 4);
            #pragma unroll
            for (int t = 0; t < TPW; ++t) {
                acc[t][r] += xa[t].x * w.x + xa[t].y * w.y
                           + xa[t].z * w.z + xa[t].w * w.w;
            }
        }

        // prefetch chunk c+2
        if (c + 2 < NCHUNK) {
            #pragma unroll
            for (int t = 0; t < TPW; ++t)
                xa[t] = ldnt(x + (size_t)(t_base + t) * DIM + (c + 2) * DC + lane * 4);
        }

        // compute chunk c+1
        #pragma unroll
        for (int r = 0; r < NR; ++r) {
            const float* wp = (r < NG) ? (Wg + (size_t)r * DIM)
                                       : (We + (size_t)(r - NG) * DIM);
            f4 w = *(const f4*)(wp + (c + 1) * DC + lane * 4);
            #pragma unroll
            for (int t = 0; t < TPW; ++t) {
                acc[t][r] += xb[t].x * w.x + xb[t].y * w.y
                           + xb[t].z * w.z + xb[t].w * w.w;
            }
        }
    }

    // ---- full-wave butterfly reduce (identical to round-0) ----
    #pragma unroll
    for (int t = 0; t < TPW; ++t)
        #pragma unroll
        for (int r = 0; r < NR; ++r) {
            float v = acc[t][r];
            #pragma unroll
            for (int s = 32; s > 0; s >>= 1) v += __shfl_xor(v, s, 64);
            acc[t][r] = v;
        }

    // ---- epilogue: tokens sequentially; scalar-only state (identical to round-0) ----
    #pragma unroll
    for (int t = 0; t < TPW; ++t) {
        // group softmax + top-1 (strict > = first-index-wins, matches np)
        float m16 = acc[t][0];
        #pragma unroll
        for (int r = 1; r < NG; ++r) m16 = fmaxf(m16, acc[t][r]);
        float den = 0.0f, bm = -1.0f; int gi = 0;
        #pragma unroll
        for (int r = 0; r < NG; ++r) {
            float e = expf(acc[t][r] - m16);
            den += e;
            if (e > bm) { bm = e; gi = r; }
        }
        float gw = bm / den;   // chosen_group_w (max softmax prob)

        // local softmax (4) + top-2
        float m4 = fmaxf(fmaxf(acc[t][NG + 0], acc[t][NG + 1]),
                         fmaxf(acc[t][NG + 2], acc[t][NG + 3]));
        float pr[GS]; float s4 = 0.0f;
        #pragma unroll
        for (int r = 0; r < GS; ++r) { pr[r] = expf(acc[t][NG + r] - m4); s4 += pr[r]; }
        float inv4 = 1.0f / s4;
        #pragma unroll
        for (int r = 0; r < GS; ++r) pr[r] *= inv4;

        int i0 = 0; float v0 = pr[0];
        #pragma unroll
        for (int r = 1; r < GS; ++r) if (pr[r] > v0) { v0 = pr[r]; i0 = r; }
        int i1 = -1; float v1 = -1.0f;
        #pragma unroll
        for (int r = 0; r < GS; ++r) if (r != i0 && pr[r] > v1) { v1 = pr[r]; i1 = r; }

        float nrm = v0 + v1 + 1e-7f;
        float sf0 = gw * (v0 / nrm);
        float sf1 = gw * (v1 / nrm);
        int   se0 = (gi << 2) + i0;
        int   se1 = (gi << 2) + i1;

        float sg = 0.0f;
        #pragma unroll
        for (int r = 0; r < NG; ++r) sg += acc[t][r] * acc[t][r];
        float sl = 0.0f;
        #pragma unroll
        for (int r = 0; r < GS; ++r) sl += acc[t][NG + r] * acc[t][NG + r];
        float sz = sg * (1.0f / 16.0f) + sl * 0.25f;   // per-token z contribution

        const long tok = t_base + t;
        if (lane < 16) {
            int col4 = lane * 4;
            float4 v;
            v.x = (col4 + 0 == se0) ? sf0 : (col4 + 0 == se1) ? sf1 : 0.0f;
            v.y = (col4 + 1 == se0) ? sf0 : (col4 + 1 == se1) ? sf1 : 0.0f;
            v.z = (col4 + 2 == se0) ? sf0 : (col4 + 2 == se1) ? sf1 : 0.0f;
            v.w = (col4 + 3 == se0) ? sf0 : (col4 + 3 == se1) ? sf1 : 0.0f;
            *(float4*)(dm_out + (size_t)tok * NE + col4) = v;  // 16 lanes x 16B = 256B row
        } else if (lane == 16) {
            *(float2*)(fw_out + tok * 2) = make_float2(sf0, sf1);
        } else if (lane == 17) {
            atomicAdd(&lds_load[se0], sf0);
        } else if (lane == 18) {
            atomicAdd(&lds_load[se1], sf1);
        } else if (lane == 19) {
            atomicAdd(&lds_z, sz);
        }
    }

    __syncthreads();
    if (tid < NE) atomicAdd(&ws[(blockIdx.x & (NSHADOW - 1)) * NE + tid], lds_load[tid]);
    if (tid == 0) atomicAdd(&ws[NSHADOW * NE], lds_z);
}

__global__ void router_finalize(const float* __restrict__ ws, float* __restrict__ out_loss)
{
    int e = threadIdx.x;  // 64 threads = 1 wave
    float load = 0.0f;
    #pragma unroll
    for (int s = 0; s < NSHADOW; ++s) load += ws[s * NE + e];
    float tot = load;
    #pragma unroll
    for (int s = 32; s > 0; s >>= 1) tot += __shfl_xor(tot, s, 64);
    float target = tot * (1.0f / NE);
    float dev = load - target;
    float sq = dev * dev;
    #pragma unroll
    for (int s = 32; s > 0; s >>= 1) sq += __shfl_xor(sq, s, 64);
    if (e == 0) {
        float lb = sq * (1.0f / NE);
        float z  = ws[NSHADOW * NE] * (1.0f / NTOK);
        out_loss[0] = 0.001f * (lb + z);
    }
}

extern "C" void kernel_launch(void* const* d_in, const int* in_sizes, int n_in,
                              void* d_out, int out_size, void* d_ws, size_t ws_size,
                              hipStream_t stream)
{
    const float* x  = (const float*)d_in[0];
    const float* Wg = (const float*)d_in[1];
    const float* We = (const float*)d_in[2];
    float* out = (float*)d_out;
    float* fw  = out;                                         // [32768, 2]
    float* dm  = out + (size_t)NTOK * 2;                      // [32768, 64]
    float* ls  = out + (size_t)NTOK * 2 + (size_t)NTOK * NE;  // [1]
    float* ws  = (float*)d_ws;

    hipMemsetAsync(ws, 0, (NSHADOW * NE + 1) * sizeof(float), stream);
    router_main<<<NTOK / TPBK, TPB, 0, stream>>>(x, Wg, We, fw, dm, ws);
    router_finalize<<<1, 64, 0, stream>>>(ws, ls);
}